// Round 1
// baseline (367.117 us; speedup 1.0000x reference)
//
#include <hip/hip_runtime.h>
#include <hip/hip_bf16.h>

typedef __attribute__((ext_vector_type(8))) short short8;
typedef __attribute__((ext_vector_type(4))) float floatx4;

#define M_DIM 8192
#define N_DIM 4096
#define K_DIM 4096
#define N_EXC 3277
#define BM 128
#define BN 128
#define BK 64

typedef unsigned int u32;
typedef __attribute__((address_space(1))) const u32 gu32;
typedef __attribute__((address_space(3))) u32 lu32;

__device__ __forceinline__ void gload_lds16(const void* g, void* l) {
    __builtin_amdgcn_global_load_lds((gu32*)g, (lu32*)l, 16, 0, 0);
}

// round-to-nearest-even f32 -> bf16 (inputs are finite; no NaN path needed)
__device__ __forceinline__ unsigned short f2bf(float f) {
    u32 u = __builtin_bit_cast(u32, f);
    u32 lsb = (u >> 16) & 1u;
    u += 0x7fffu + lsb;
    return (unsigned short)(u >> 16);
}

// ---------------------------------------------------------------------------
// Detect on-device dtype of the boolean `kernel` input.
// flag: 0 = int32, 1 = bool/u8, 2 = float32
__global__ void detect_kind(const unsigned char* __restrict__ w, int* __restrict__ flag) {
    __shared__ int sF, sO;
    const int tid = threadIdx.x;
    if (tid == 0) { sF = 0; sO = 0; }
    __syncthreads();
    int sawF = 0, sawO = 0;
    const unsigned char* p = w + tid * 16;
    #pragma unroll
    for (int i = 0; i < 16; ++i) {
        unsigned char b = p[i];
        int off = (tid * 16 + i) & 3;
        if (b == 0x3F && off == 3) sawF = 1;     // float32 1.0f high byte
        if (b != 0 && off != 0)    sawO = 1;     // non-word-aligned payload
    }
    if (sawF) atomicOr(&sF, 1);
    if (sawO) atomicOr(&sO, 1);
    __syncthreads();
    if (tid == 0) *flag = sF ? 2 : (sO ? 1 : 0);
}

// ---------------------------------------------------------------------------
// x (f32, [M][K]) -> xb (bf16, [M][K]) with EI column scaling.
__global__ void conv_x_kernel(const float* __restrict__ x, unsigned short* __restrict__ xb) {
    size_t base = ((size_t)blockIdx.x * 256 + threadIdx.x) * 8;
    int k = (int)(base & (K_DIM - 1));   // 8 | 4096, so k..k+7 stay in-row
    floatx4 v0 = *(const floatx4*)(x + base);
    floatx4 v1 = *(const floatx4*)(x + base + 4);
    float f[8];
    f[0] = v0[0]; f[1] = v0[1]; f[2] = v0[2]; f[3] = v0[3];
    f[4] = v1[0]; f[5] = v1[1]; f[6] = v1[2]; f[7] = v1[3];
    short8 o;
    #pragma unroll
    for (int j = 0; j < 8; ++j) {
        float val = (k + j < N_EXC) ? f[j] : -4.0f * f[j];
        o[j] = (short)f2bf(val);
    }
    *(short8*)(xb + base) = o;
}

// ---------------------------------------------------------------------------
// kernel ([K][N], dtype per flag) -> wbt (bf16, [N][K]) transposed via LDS tile.
__global__ void conv_w_kernel(const void* __restrict__ w, const int* __restrict__ flag,
                              unsigned short* __restrict__ wbt) {
    __shared__ unsigned short t[64][65];
    const int kind = *flag;
    const int tid = threadIdx.x;
    const int bx = blockIdx.x & 63;    // n-tile
    const int by = blockIdx.x >> 6;    // k-tile
    const int k0 = by * 64, n0 = bx * 64;
    #pragma unroll
    for (int i = 0; i < 16; ++i) {
        int lin = i * 256 + tid;
        int r = lin >> 6, c = lin & 63;
        size_t gi = (size_t)(k0 + r) * N_DIM + (n0 + c);
        float val;
        if (kind == 0)      val = (float)((const int*)w)[gi];
        else if (kind == 1) val = (float)((const unsigned char*)w)[gi];
        else                val = ((const float*)w)[gi];
        t[r][c] = f2bf(val);
    }
    __syncthreads();
    #pragma unroll
    for (int i = 0; i < 16; ++i) {
        int lin = i * 256 + tid;
        int rr = lin >> 6, cc = lin & 63;
        wbt[(size_t)(n0 + rr) * K_DIM + (k0 + cc)] = t[cc][rr];
    }
}

// ---------------------------------------------------------------------------
// bf16 GEMM: C[M][N] = scale * A[M][K] x Bt[N][K]^T
// 128x128 tile, BK=64, 4 waves (each 64x64), 16x16x32 MFMA, global_load_lds.
__global__ void gemm_kernel(const unsigned short* __restrict__ A,
                            const unsigned short* __restrict__ Bt,
                            float* __restrict__ C,
                            const float* __restrict__ scale_p) {
    __shared__ __align__(16) unsigned short As[BM][BK];
    __shared__ __align__(16) unsigned short Bs[BN][BK];

    const int tid  = threadIdx.x;
    const int wid  = tid >> 6;
    const int lane = tid & 63;
    const int l15  = lane & 15;
    const int l4   = lane >> 4;

    // XCD-aware swizzle (2048 blocks, divisible by 8 -> bijective)
    const int nwg = gridDim.x;
    const int cpx = nwg >> 3;
    int wg = blockIdx.x;
    wg = (wg & 7) * cpx + (wg >> 3);
    const int bm = wg >> 5;        // 64 m-tiles
    const int bn = wg & 31;        // 32 n-tiles

    const int wr = wid >> 1, wc = wid & 1;
    const int row0 = bm * BM + wr * 64;
    const int col0 = bn * BN + wc * 64;

    floatx4 acc[4][4] = {};

    const size_t a_base = (size_t)(bm * BM) * K_DIM;
    const size_t b_base = (size_t)(bn * BN) * K_DIM;

    for (int kt = 0; kt < K_DIM; kt += BK) {
        // stage A-tile (16 KiB) and B-tile (16 KiB), 4 gload_lds rounds each
        #pragma unroll
        for (int c = 0; c < 4; ++c) {
            int t2 = c * 256 + tid;
            int r = t2 >> 3, s = t2 & 7;
            const unsigned short* ga = A + a_base + (size_t)r * K_DIM + kt + s * 8;
            gload_lds16(ga, (char*)&As[0][0] + c * 4096 + wid * 1024);
            const unsigned short* gb = Bt + b_base + (size_t)r * K_DIM + kt + s * 8;
            gload_lds16(gb, (char*)&Bs[0][0] + c * 4096 + wid * 1024);
        }
        __syncthreads();   // compiler drains vmcnt before barrier

        #pragma unroll
        for (int kk = 0; kk < 2; ++kk) {
            short8 a[4], b[4];
            #pragma unroll
            for (int mi = 0; mi < 4; ++mi)
                a[mi] = *(const short8*)&As[wr * 64 + mi * 16 + l15][kk * 32 + l4 * 8];
            #pragma unroll
            for (int ni = 0; ni < 4; ++ni)
                b[ni] = *(const short8*)&Bs[wc * 64 + ni * 16 + l15][kk * 32 + l4 * 8];
            #pragma unroll
            for (int mi = 0; mi < 4; ++mi)
                #pragma unroll
                for (int ni = 0; ni < 4; ++ni)
                    acc[mi][ni] = __builtin_amdgcn_mfma_f32_16x16x32_bf16(
                        a[mi], b[ni], acc[mi][ni], 0, 0, 0);
        }
        __syncthreads();   // protect LDS before next stage
    }

    const float s = *scale_p;
    #pragma unroll
    for (int mi = 0; mi < 4; ++mi) {
        #pragma unroll
        for (int ni = 0; ni < 4; ++ni) {
            int row = row0 + mi * 16 + l4 * 4;
            int col = col0 + ni * 16 + l15;
            float* cp = C + (size_t)row * N_DIM + col;
            #pragma unroll
            for (int r = 0; r < 4; ++r)
                cp[(size_t)r * N_DIM] = s * acc[mi][ni][r];
        }
    }
}

// ---------------------------------------------------------------------------
// Insurance fallback if workspace is too small: naive fp32, correct but slow.
__global__ void naive_kernel(const float* __restrict__ x, const void* __restrict__ w,
                             const int* __restrict__ flag, const float* __restrict__ scale_p,
                             float* __restrict__ out) {
    int n = blockIdx.x * 256 + threadIdx.x;
    int m = blockIdx.y;
    int kind = *flag;
    const float* xr = x + (size_t)m * K_DIM;
    float acc = 0.f;
    for (int k = 0; k < K_DIM; ++k) {
        float xv = xr[k];
        if (k >= N_EXC) xv = -4.0f * xv;
        size_t gi = (size_t)k * N_DIM + n;
        float wv;
        if (kind == 0)      wv = (float)((const int*)w)[gi];
        else if (kind == 1) wv = (float)((const unsigned char*)w)[gi];
        else                wv = ((const float*)w)[gi];
        acc += xv * wv;
    }
    out[(size_t)m * N_DIM + n] = acc * (*scale_p);
}

extern "C" void kernel_launch(void* const* d_in, const int* in_sizes, int n_in,
                              void* d_out, int out_size, void* d_ws, size_t ws_size,
                              hipStream_t stream) {
    const float* x       = (const float*)d_in[0];
    const void*  w       = d_in[1];
    const float* scale_p = (const float*)d_in[2];
    float* out = (float*)d_out;

    const size_t xb_bytes = (size_t)M_DIM * K_DIM * 2;   // 64 MiB
    const size_t wb_bytes = (size_t)N_DIM * K_DIM * 2;   // 32 MiB
    const size_t need = xb_bytes + wb_bytes + 256;

    if (ws_size >= need) {
        unsigned short* xb  = (unsigned short*)d_ws;
        unsigned short* wbt = (unsigned short*)((char*)d_ws + xb_bytes);
        int* flag = (int*)((char*)d_ws + xb_bytes + wb_bytes);
        detect_kind<<<1, 256, 0, stream>>>((const unsigned char*)w, flag);
        conv_x_kernel<<<(M_DIM * K_DIM) / (256 * 8), 256, 0, stream>>>(x, xb);
        conv_w_kernel<<<(K_DIM / 64) * (N_DIM / 64), 256, 0, stream>>>(w, flag, wbt);
        gemm_kernel<<<(M_DIM / BM) * (N_DIM / BN), 256, 0, stream>>>(xb, wbt, out, scale_p);
    } else if (ws_size >= 4) {
        int* flag = (int*)d_ws;
        detect_kind<<<1, 256, 0, stream>>>((const unsigned char*)w, flag);
        dim3 g(N_DIM / 256, M_DIM);
        naive_kernel<<<g, 256, 0, stream>>>(x, w, flag, scale_p, out);
    }
}

// Round 2
// 274.021 us; speedup vs baseline: 1.3397x; 1.3397x over previous
//
#include <hip/hip_runtime.h>
#include <hip/hip_bf16.h>

typedef __attribute__((ext_vector_type(8))) short short8;
typedef __attribute__((ext_vector_type(4))) float floatx4;

#define M_DIM 8192
#define N_DIM 4096
#define K_DIM 4096
#define N_EXC 3277

typedef unsigned int u32;
typedef __attribute__((address_space(1))) const u32 gu32;
typedef __attribute__((address_space(3))) u32 lu32;

__device__ __forceinline__ void gload_lds16(const void* g, void* l) {
    __builtin_amdgcn_global_load_lds((gu32*)g, (lu32*)l, 16, 0, 0);
}

// round-to-nearest-even f32 -> bf16 (inputs finite)
__device__ __forceinline__ unsigned short f2bf(float f) {
    u32 u = __builtin_bit_cast(u32, f);
    u32 lsb = (u >> 16) & 1u;
    u += 0x7fffu + lsb;
    return (unsigned short)(u >> 16);
}

// ---------------------------------------------------------------------------
// flag: 0 = int32, 1 = bool/u8, 2 = float32
__global__ void detect_kind(const unsigned char* __restrict__ w, int* __restrict__ flag) {
    __shared__ int sF, sO;
    const int tid = threadIdx.x;
    if (tid == 0) { sF = 0; sO = 0; }
    __syncthreads();
    int sawF = 0, sawO = 0;
    const unsigned char* p = w + tid * 16;
    #pragma unroll
    for (int i = 0; i < 16; ++i) {
        unsigned char b = p[i];
        int off = (tid * 16 + i) & 3;
        if (b == 0x3F && off == 3) sawF = 1;
        if (b != 0 && off != 0)    sawO = 1;
    }
    if (sawF) atomicOr(&sF, 1);
    if (sawO) atomicOr(&sO, 1);
    __syncthreads();
    if (tid == 0) *flag = sF ? 2 : (sO ? 1 : 0);
}

// ---------------------------------------------------------------------------
// x (f32, [M][K]) -> xb (bf16, [M][K]) with EI column scaling.
__global__ void conv_x_kernel(const float* __restrict__ x, unsigned short* __restrict__ xb) {
    size_t base = ((size_t)blockIdx.x * 256 + threadIdx.x) * 8;
    int k = (int)(base & (K_DIM - 1));
    floatx4 v0 = *(const floatx4*)(x + base);
    floatx4 v1 = *(const floatx4*)(x + base + 4);
    float f[8];
    f[0] = v0[0]; f[1] = v0[1]; f[2] = v0[2]; f[3] = v0[3];
    f[4] = v1[0]; f[5] = v1[1]; f[6] = v1[2]; f[7] = v1[3];
    short8 o;
    #pragma unroll
    for (int j = 0; j < 8; ++j) {
        float val = (k + j < N_EXC) ? f[j] : -4.0f * f[j];
        o[j] = (short)f2bf(val);
    }
    *(short8*)(xb + base) = o;
}

// ---------------------------------------------------------------------------
// kernel ([K][N], dtype per flag) -> wbt (bf16, [N][K]) transposed via LDS tile.
__global__ void conv_w_kernel(const void* __restrict__ w, const int* __restrict__ flag,
                              unsigned short* __restrict__ wbt) {
    __shared__ unsigned short t[64][65];
    const int kind = *flag;
    const int tid = threadIdx.x;
    const int bx = blockIdx.x & 63;
    const int by = blockIdx.x >> 6;
    const int k0 = by * 64, n0 = bx * 64;
    #pragma unroll
    for (int i = 0; i < 16; ++i) {
        int lin = i * 256 + tid;
        int r = lin >> 6, c = lin & 63;
        size_t gi = (size_t)(k0 + r) * N_DIM + (n0 + c);
        float val;
        if (kind == 0)      val = (float)((const int*)w)[gi];
        else if (kind == 1) val = (float)((const unsigned char*)w)[gi];
        else                val = ((const float*)w)[gi];
        t[r][c] = f2bf(val);
    }
    __syncthreads();
    #pragma unroll
    for (int i = 0; i < 16; ++i) {
        int lin = i * 256 + tid;
        int rr = lin >> 6, cc = lin & 63;
        wbt[(size_t)(n0 + rr) * K_DIM + (k0 + cc)] = t[cc][rr];
    }
}

// ---------------------------------------------------------------------------
// 256x256 tile, BK=64, 8 waves (2x4), 8-phase schedule, XOR-swizzled LDS.
// C[M][N] = scale * A[M][K] x Bt[N][K]^T
//
// Region retirement (quadrants (mh,nh) in order (0,0),(0,1),(1,1),(1,0)):
//   A-lo (mh0 rows) retired ph2 (read ph1, regs reused ph2)
//   A-hi retired ph4 ; B-hi (nh1) retired ph3 ; B-lo (nh0) retired ph4
// Stage schedule (issue strictly after retirement, land enforced by vmcnt):
//   ph1: T+1 B-lo -> buf1   ph2: T+1 A-hi -> buf1
//   ph3: T+2 A-lo -> buf0   ph4: T+2 B-hi -> buf0   [vmcnt(4): T+1 landed]
//   ph5: T+2 B-lo -> buf0   ph6: T+2 A-hi -> buf0
//   ph7: T+3 A-lo -> buf1   ph8: T+3 B-hi -> buf1   [vmcnt(4): T+2 landed]
__global__ __launch_bounds__(512, 2)
void gemm8_kernel(const unsigned short* __restrict__ A,
                  const unsigned short* __restrict__ Bt,
                  float* __restrict__ C,
                  const float* __restrict__ scale_p) {
    __shared__ __align__(16) char lds[131072];   // 2 bufs x (A 32K + B 32K)

    const int tid  = threadIdx.x;
    const int wid  = tid >> 6;
    const int lane = tid & 63;
    const int l15  = lane & 15;
    const int l4   = lane >> 4;
    const int wr   = wid >> 2;      // 0..1  (128-row half)
    const int wc   = wid & 3;       // 0..3  (64-col quarter)

    // XCD swizzle: 512 blocks, 8 XCDs, 64 blocks per XCD chunk (bijective)
    int wg = blockIdx.x;
    wg = (wg & 7) * 64 + (wg >> 3);
    const int bm = wg >> 4;         // 32 m-tiles
    const int bn = wg & 15;         // 16 n-tiles

    const size_t a_base = (size_t)bm * 256 * K_DIM;
    const size_t b_base = (size_t)bn * 256 * K_DIM;

    // staging: unit u = wid*2+j covers 8 rows (1 KiB); lane -> row l>>3, slot l&7
    const int u0   = wid * 2;
    const int lrow = lane >> 3;                        // 0..7
    const int lswz = ((lane & 7) ^ lrow) << 3;         // pre-swizzled source col (elems)
    const int xm   = (l15 & 7) << 4;                   // read-side xor (row&7)<<4

// ---- staging macros (2 x global_load_lds each; LDS dest linear, src pre-swizzled)
#define STAGEA(BUF, TILE, HALF) do { \
    _Pragma("unroll") \
    for (int j_ = 0; j_ < 2; ++j_) { \
        int u_ = u0 + j_; \
        int r0_ = (HALF)*64 + ((u_ & 8) << 4) + ((u_ & 7) << 3); \
        const unsigned short* g_ = A + a_base + (size_t)(r0_ + lrow) * K_DIM + (TILE)*64 + lswz; \
        gload_lds16(g_, lds + (BUF)*65536 + r0_*128); \
    } } while (0)

#define STAGEB(BUF, TILE, HALF) do { \
    _Pragma("unroll") \
    for (int j_ = 0; j_ < 2; ++j_) { \
        int u_ = u0 + j_; \
        int r0_ = (HALF)*32 + ((u_ >> 2) << 6) + ((u_ & 3) << 3); \
        const unsigned short* g_ = Bt + b_base + (size_t)(r0_ + lrow) * K_DIM + (TILE)*64 + lswz; \
        gload_lds16(g_, lds + (BUF)*65536 + 32768 + r0_*128); \
    } } while (0)

// ---- fragment loads (swizzled ds_read_b128)
#define LDA_(BUF, MH) do { \
    const int rb_ = wr*128 + (MH)*64; \
    _Pragma("unroll") \
    for (int mi_ = 0; mi_ < 4; ++mi_) { \
        _Pragma("unroll") \
        for (int kk_ = 0; kk_ < 2; ++kk_) \
            ar[mi_][kk_] = *(const short8*)(lds + (BUF)*65536 \
                + (rb_ + mi_*16 + l15)*128 + (((kk_<<6)|(l4<<4)) ^ xm)); \
    } } while (0)

#define LDB_(BUF, NH) do { \
    const int rb_ = wc*64 + (NH)*32; \
    _Pragma("unroll") \
    for (int ni_ = 0; ni_ < 2; ++ni_) { \
        _Pragma("unroll") \
        for (int kk_ = 0; kk_ < 2; ++kk_) \
            br[ni_][kk_] = *(const short8*)(lds + (BUF)*65536 + 32768 \
                + (rb_ + ni_*16 + l15)*128 + (((kk_<<6)|(l4<<4)) ^ xm)); \
    } } while (0)

#define MFMA16(MH, NH) do { \
    __builtin_amdgcn_s_setprio(1); \
    _Pragma("unroll") \
    for (int mi_ = 0; mi_ < 4; ++mi_) { \
        _Pragma("unroll") \
        for (int ni_ = 0; ni_ < 2; ++ni_) { \
            _Pragma("unroll") \
            for (int kk_ = 0; kk_ < 2; ++kk_) \
                acc[(MH)*4+mi_][(NH)*2+ni_] = __builtin_amdgcn_mfma_f32_16x16x32_bf16( \
                    ar[mi_][kk_], br[ni_][kk_], acc[(MH)*4+mi_][(NH)*2+ni_], 0, 0, 0); \
    } } \
    __builtin_amdgcn_s_setprio(0); } while (0)

#define BAR()   __builtin_amdgcn_s_barrier()
#define LGKM0() do { asm volatile("s_waitcnt lgkmcnt(0)" ::: "memory"); \
                     __builtin_amdgcn_sched_barrier(0); } while (0)
#define VM4()   asm volatile("s_waitcnt vmcnt(4)" ::: "memory")

    short8 ar[4][2], br[2][2];
    floatx4 acc[8][4] = {};

    // prologue: tile0 full -> buf0; tile1 A-lo + B-hi -> buf1; drain tile0
    STAGEA(0, 0, 0);
    STAGEB(0, 0, 1);
    STAGEB(0, 0, 0);
    STAGEA(0, 0, 1);
    STAGEA(1, 1, 0);
    STAGEB(1, 1, 1);
    VM4();
    BAR();

    for (int i = 0; i < 32; ++i) {
        const int t1 = (2*i + 1) & 63;
        const int t2 = (2*i + 2) & 63;   // wrap on last iters: WAR-safe, never read
        const int t3 = (2*i + 3) & 63;
        // ph1
        LDA_(0, 0); LDB_(0, 0); STAGEB(1, t1, 0);
        BAR(); LGKM0(); MFMA16(0, 0); BAR();
        // ph2
        LDB_(0, 1); STAGEA(1, t1, 1);
        BAR(); LGKM0(); MFMA16(0, 1); BAR();
        // ph3
        LDA_(0, 1); STAGEA(0, t2, 0);
        BAR(); LGKM0(); MFMA16(1, 1); BAR();
        // ph4
        LDB_(0, 0); STAGEB(0, t2, 1);
        BAR(); LGKM0(); MFMA16(1, 0); VM4(); BAR();
        // ph5
        LDA_(1, 0); LDB_(1, 0); STAGEB(0, t2, 0);
        BAR(); LGKM0(); MFMA16(0, 0); BAR();
        // ph6
        LDB_(1, 1); STAGEA(0, t2, 1);
        BAR(); LGKM0(); MFMA16(0, 1); BAR();
        // ph7
        LDA_(1, 1); STAGEA(1, t3, 0);
        BAR(); LGKM0(); MFMA16(1, 1); BAR();
        // ph8
        LDB_(1, 0); STAGEB(1, t3, 1);
        BAR(); LGKM0(); MFMA16(1, 0); VM4(); BAR();
    }
    asm volatile("s_waitcnt vmcnt(0)" ::: "memory");
    BAR();

    // epilogue
    const float s = *scale_p;
    const int row0 = bm * 256 + wr * 128;
    const int col0 = bn * 256 + wc * 64;
    #pragma unroll
    for (int mf = 0; mf < 8; ++mf) {
        #pragma unroll
        for (int nf = 0; nf < 4; ++nf) {
            int row = row0 + mf * 16 + l4 * 4;
            int col = col0 + nf * 16 + l15;
            float* cp = C + (size_t)row * N_DIM + col;
            #pragma unroll
            for (int r = 0; r < 4; ++r)
                cp[(size_t)r * N_DIM] = s * acc[mf][nf][r];
        }
    }
#undef STAGEA
#undef STAGEB
#undef LDA_
#undef LDB_
#undef MFMA16
#undef BAR
#undef LGKM0
#undef VM4
}

// ---------------------------------------------------------------------------
// Insurance fallback if workspace is too small: naive fp32, correct but slow.
__global__ void naive_kernel(const float* __restrict__ x, const void* __restrict__ w,
                             const int* __restrict__ flag, const float* __restrict__ scale_p,
                             float* __restrict__ out) {
    int n = blockIdx.x * 256 + threadIdx.x;
    int m = blockIdx.y;
    int kind = *flag;
    const float* xr = x + (size_t)m * K_DIM;
    float acc = 0.f;
    for (int k = 0; k < K_DIM; ++k) {
        float xv = xr[k];
        if (k >= N_EXC) xv = -4.0f * xv;
        size_t gi = (size_t)k * N_DIM + n;
        float wv;
        if (kind == 0)      wv = (float)((const int*)w)[gi];
        else if (kind == 1) wv = (float)((const unsigned char*)w)[gi];
        else                wv = ((const float*)w)[gi];
        acc += xv * wv;
    }
    out[(size_t)m * N_DIM + n] = acc * (*scale_p);
}

extern "C" void kernel_launch(void* const* d_in, const int* in_sizes, int n_in,
                              void* d_out, int out_size, void* d_ws, size_t ws_size,
                              hipStream_t stream) {
    const float* x       = (const float*)d_in[0];
    const void*  w       = d_in[1];
    const float* scale_p = (const float*)d_in[2];
    float* out = (float*)d_out;

    const size_t xb_bytes = (size_t)M_DIM * K_DIM * 2;   // 64 MiB
    const size_t wb_bytes = (size_t)N_DIM * K_DIM * 2;   // 32 MiB
    const size_t need = xb_bytes + wb_bytes + 256;

    if (ws_size >= need) {
        unsigned short* xb  = (unsigned short*)d_ws;
        unsigned short* wbt = (unsigned short*)((char*)d_ws + xb_bytes);
        int* flag = (int*)((char*)d_ws + xb_bytes + wb_bytes);
        detect_kind<<<1, 256, 0, stream>>>((const unsigned char*)w, flag);
        conv_x_kernel<<<(M_DIM * K_DIM) / (256 * 8), 256, 0, stream>>>(x, xb);
        conv_w_kernel<<<(K_DIM / 64) * (N_DIM / 64), 256, 0, stream>>>(w, flag, wbt);
        gemm8_kernel<<<(M_DIM / 256) * (N_DIM / 256), 512, 0, stream>>>(xb, wbt, out, scale_p);
    } else if (ws_size >= 4) {
        int* flag = (int*)d_ws;
        detect_kind<<<1, 256, 0, stream>>>((const unsigned char*)w, flag);
        dim3 g(N_DIM / 256, M_DIM);
        naive_kernel<<<g, 256, 0, stream>>>(x, w, flag, scale_p, out);
    }
}